// Round 1
// baseline (234.501 us; speedup 1.0000x reference)
//
#include <hip/hip_runtime.h>
#include <hip/hip_bf16.h>

#define IN_F  4096
#define OUT_F 4096
#define NTOK  4096
#define RANK  32
#define GS    64
#define NG    64            // groups per row
#define KTOT  4160          // 4096 + 32 (low-rank) + 32 (zero pad) -> 65 * 64

typedef __attribute__((ext_vector_type(4))) float f32x4;
typedef __attribute__((ext_vector_type(8))) short bf16x8;

__device__ __forceinline__ ushort f2bf(float f) {
  union { float f; uint u; } c; c.f = f;
  const uint u = c.u;
  return (ushort)((u + 0x7fffu + ((u >> 16) & 1u)) >> 16);  // RNE
}

// ---------------------------------------------------------------------------
// Kernel 1: per-group int8 quant + dequant of x -> A_ext[:, 0:4096] (bf16)
// One 16-lane group handles one 64-elem quant group (4 floats/lane).
// ---------------------------------------------------------------------------
__global__ __launch_bounds__(256)
void quant_kernel(const float* __restrict__ x, ushort* __restrict__ Aext)
{
  const int tid  = threadIdx.x;
  const int wave = tid >> 6, lane = tid & 63;
  const int sub  = lane & 15;
  const int ggrp = blockIdx.x * 16 + wave * 4 + (lane >> 4);
  const int row  = ggrp >> 6, g = ggrp & 63;

  const float4 v = *(const float4*)(x + (size_t)row * IN_F + g * GS + sub * 4);
  float m = fmaxf(fmaxf(fabsf(v.x), fabsf(v.y)), fmaxf(fabsf(v.z), fabsf(v.w)));
  m = fmaxf(m, __shfl_xor(m, 1));
  m = fmaxf(m, __shfl_xor(m, 2));
  m = fmaxf(m, __shfl_xor(m, 4));
  m = fmaxf(m, __shfl_xor(m, 8));
  const float ascale = (m > 0.f) ? m * (1.f / 127.f) : 1.f;

  const float d0 = fminf(fmaxf(rintf(v.x / ascale), -127.f), 127.f) * ascale;
  const float d1 = fminf(fmaxf(rintf(v.y / ascale), -127.f), 127.f) * ascale;
  const float d2 = fminf(fmaxf(rintf(v.z / ascale), -127.f), 127.f) * ascale;
  const float d3 = fminf(fmaxf(rintf(v.w / ascale), -127.f), 127.f) * ascale;

  uint2 st;
  st.x = (uint)f2bf(d0) | ((uint)f2bf(d1) << 16);
  st.y = (uint)f2bf(d2) | ((uint)f2bf(d3) << 16);
  *(uint2*)(Aext + (size_t)row * KTOT + g * GS + sub * 4) = st;
}

// ---------------------------------------------------------------------------
// Kernel 2: dequant int4 weights -> B_ext[:, 0:4096] (bf16). 8 elems/thread.
// ---------------------------------------------------------------------------
__global__ __launch_bounds__(256)
void wdeq_kernel(const int* __restrict__ qw, const float* __restrict__ wsc,
                 ushort* __restrict__ Bext)
{
  const int gidx = blockIdx.x * 256 + threadIdx.x;   // over OUT_F * 512
  const int o  = gidx >> 9;
  const int i0 = (gidx & 511) << 3;
  const float sc = wsc[o * NG + (i0 >> 6)];
  const int4 qa = *(const int4*)(qw + (size_t)o * IN_F + i0);
  const int4 qb = *(const int4*)(qw + (size_t)o * IN_F + i0 + 4);
  uint4 st;
  st.x = (uint)f2bf(qa.x * sc) | ((uint)f2bf(qa.y * sc) << 16);
  st.y = (uint)f2bf(qa.z * sc) | ((uint)f2bf(qa.w * sc) << 16);
  st.z = (uint)f2bf(qb.x * sc) | ((uint)f2bf(qb.y * sc) << 16);
  st.w = (uint)f2bf(qb.z * sc) | ((uint)f2bf(qb.w * sc) << 16);
  *(uint4*)(Bext + (size_t)o * KTOT + i0) = st;
}

// ---------------------------------------------------------------------------
// Kernel 3: lr = x @ proj_down -> A_ext[:, 4096:4128] (bf16), zero 4128:4160.
// 8 rows per block; thread (s = kslice, r = rank).
// ---------------------------------------------------------------------------
__global__ __launch_bounds__(256)
void lowrank_kernel(const float* __restrict__ x, const float* __restrict__ pd,
                    ushort* __restrict__ Aext)
{
  const int t = threadIdx.x;
  const int r = t & 31, s = t >> 5;
  const int row0 = blockIdx.x * 8;
  float acc[8] = {0.f,0.f,0.f,0.f,0.f,0.f,0.f,0.f};
  const int kbase = s * 512;
  for (int kk = 0; kk < 512; ++kk) {
    const int k = kbase + kk;
    const float pdv = pd[k * RANK + r];
    #pragma unroll
    for (int q = 0; q < 8; ++q)
      acc[q] = fmaf(x[(size_t)(row0 + q) * IN_F + k], pdv, acc[q]);
  }
  __shared__ float red[8][8][32];
  #pragma unroll
  for (int q = 0; q < 8; ++q) red[s][q][r] = acc[q];
  __syncthreads();
  const int qr = t >> 5, rr = t & 31;
  float sum = 0.f;
  #pragma unroll
  for (int ss = 0; ss < 8; ++ss) sum += red[ss][qr][rr];
  ushort* dst = Aext + (size_t)(row0 + qr) * KTOT + IN_F;
  dst[rr] = f2bf(sum);
  dst[RANK + rr] = 0;
}

// ---------------------------------------------------------------------------
// Kernel 4: B_ext[:, 4096:4128] = proj_up^T (bf16), zero 4128:4160.
// ---------------------------------------------------------------------------
__global__ __launch_bounds__(256)
void pu_kernel(const float* __restrict__ pu, ushort* __restrict__ Bext)
{
  const int o = blockIdx.x * 256 + threadIdx.x;
  ushort* dst = Bext + (size_t)o * KTOT + IN_F;
  #pragma unroll
  for (int r = 0; r < RANK; ++r) {
    dst[r]        = f2bf(pu[(size_t)r * OUT_F + o]);
    dst[RANK + r] = 0;
  }
}

// ---------------------------------------------------------------------------
// Kernel 5: C = A_ext @ B_ext^T + bias.  128x128 tile, BK=64, 4 waves,
// global_load_lds(16B) staging, XOR-swizzled LDS (G4), 16x16x32 bf16 MFMA.
// Swizzle rule #21: linear LDS dest + inverse-swizzled GLOBAL source chunks
// + the same XOR on ds_read.
// ---------------------------------------------------------------------------
__global__ __launch_bounds__(256, 2)
void gemm_kernel(const ushort* __restrict__ A, const ushort* __restrict__ B,
                 const float* __restrict__ bias, float* __restrict__ C)
{
  __shared__ alignas(16) ushort lA[128 * 64];
  __shared__ alignas(16) ushort lB[128 * 64];
  const int tid  = threadIdx.x;
  const int wave = tid >> 6, lane = tid & 63;
  const int bm = blockIdx.x >> 5, bn = blockIdx.x & 31;
  const int wm = wave >> 1, wn = wave & 1;

  // staging: thread covers LDS linear bytes t*16 (+ j*4096); row = t>>3,
  // chunk cc = t&7; source chunk = cc ^ (row&7)  (j adds 32 rows; (row&7) inv)
  const int tr  = tid >> 3;
  const int scc = (tid & 7) ^ (tr & 7);
  const ushort* aSrc = A + (size_t)(bm * 128 + tr) * KTOT + scc * 8;
  const ushort* bSrc = B + (size_t)(bn * 128 + tr) * KTOT + scc * 8;
  char* ldsA = (char*)lA + wave * 1024;   // wave-uniform LDS bases
  char* ldsB = (char*)lB + wave * 1024;

  f32x4 acc[4][4];
  #pragma unroll
  for (int m = 0; m < 4; ++m)
    #pragma unroll
    for (int n = 0; n < 4; ++n)
      acc[m][n] = f32x4{0.f, 0.f, 0.f, 0.f};

  for (int kt = 0; kt < KTOT / 64; ++kt) {
    const ushort* aS = aSrc + kt * 64;
    const ushort* bS = bSrc + kt * 64;
    #pragma unroll
    for (int j = 0; j < 4; ++j)
      __builtin_amdgcn_global_load_lds(
          (const __attribute__((address_space(1))) void*)(aS + (size_t)j * 32 * KTOT),
          (__attribute__((address_space(3))) void*)(ldsA + j * 4096), 16, 0, 0);
    #pragma unroll
    for (int j = 0; j < 4; ++j)
      __builtin_amdgcn_global_load_lds(
          (const __attribute__((address_space(1))) void*)(bS + (size_t)j * 32 * KTOT),
          (__attribute__((address_space(3))) void*)(ldsB + j * 4096), 16, 0, 0);
    __syncthreads();

    #pragma unroll
    for (int ks = 0; ks < 2; ++ks) {
      const int kb = (ks * 32 + (lane >> 4) * 8) * 2;   // byte offset of k
      bf16x8 af[4], bfr[4];
      #pragma unroll
      for (int m = 0; m < 4; ++m) {
        const int row  = wm * 64 + m * 16 + (lane & 15);
        const int addr = (row * 128 + kb) ^ ((row & 7) << 4);
        af[m] = *(const bf16x8*)((const char*)lA + addr);
      }
      #pragma unroll
      for (int n = 0; n < 4; ++n) {
        const int row  = wn * 64 + n * 16 + (lane & 15);
        const int addr = (row * 128 + kb) ^ ((row & 7) << 4);
        bfr[n] = *(const bf16x8*)((const char*)lB + addr);
      }
      #pragma unroll
      for (int m = 0; m < 4; ++m)
        #pragma unroll
        for (int n = 0; n < 4; ++n)
          acc[m][n] = __builtin_amdgcn_mfma_f32_16x16x32_bf16(af[m], bfr[n], acc[m][n], 0, 0, 0);
    }
    __syncthreads();
  }

  // epilogue: C = acc + bias.  acc layout: col = lane&15, row = (lane>>4)*4+i
  const int col0  = bn * 128 + wn * 64 + (lane & 15);
  const int rbase = bm * 128 + wm * 64 + (lane >> 4) * 4;
  #pragma unroll
  for (int n = 0; n < 4; ++n) {
    const float bv = bias[col0 + n * 16];
    #pragma unroll
    for (int m = 0; m < 4; ++m) {
      #pragma unroll
      for (int i = 0; i < 4; ++i)
        C[(size_t)(rbase + m * 16 + i) * OUT_F + col0 + n * 16] = acc[m][n][i] + bv;
    }
  }
}

// ---------------------------------------------------------------------------
extern "C" void kernel_launch(void* const* d_in, const int* in_sizes, int n_in,
                              void* d_out, int out_size, void* d_ws, size_t ws_size,
                              hipStream_t stream) {
  const float* x    = (const float*)d_in[0];
  const int*   qw   = (const int*)d_in[1];
  const float* wsc  = (const float*)d_in[2];
  const float* bias = (const float*)d_in[3];
  const float* pd   = (const float*)d_in[4];
  const float* pu   = (const float*)d_in[5];
  float* out = (float*)d_out;

  ushort* Aext = (ushort*)d_ws;                       // [4096][4160] bf16
  ushort* Bext = Aext + (size_t)NTOK * KTOT;          // [4096][4160] bf16

  quant_kernel  <<<16384, 256, 0, stream>>>(x, Aext);
  wdeq_kernel   <<< 8192, 256, 0, stream>>>(qw, wsc, Bext);
  lowrank_kernel<<<  512, 256, 0, stream>>>(x, pd, Aext);
  pu_kernel     <<<   16, 256, 0, stream>>>(pu, Bext);
  gemm_kernel   <<< 1024, 256, 0, stream>>>(Aext, Bext, bias, out);
}

// Round 2
// 203.133 us; speedup vs baseline: 1.1544x; 1.1544x over previous
//
#include <hip/hip_runtime.h>
#include <hip/hip_bf16.h>

#define IN_F  4096
#define OUT_F 4096
#define NTOK  4096
#define RANK  32
#define GS    64
#define NG    64            // groups per row
#define KTOT  4160          // 4096 + 32 (low-rank) + 32 (zero pad) -> 65 * 64
#define KCH   1024          // K-chunk for lr kernel

typedef __attribute__((ext_vector_type(4))) float f32x4;
typedef __attribute__((ext_vector_type(8))) short bf16x8;

__device__ __forceinline__ ushort f2bf(float f) {
  union { float f; uint u; } c; c.f = f;
  const uint u = c.u;
  return (ushort)((u + 0x7fffu + ((u >> 16) & 1u)) >> 16);  // RNE
}

// ---------------------------------------------------------------------------
// Kernel 1: per-group int8 quant + dequant of x -> A_ext[:, 0:4096] (bf16)
// One 16-lane group handles one 64-elem quant group (4 floats/lane).
// ---------------------------------------------------------------------------
__global__ __launch_bounds__(256)
void quant_kernel(const float* __restrict__ x, ushort* __restrict__ Aext)
{
  const int tid  = threadIdx.x;
  const int wave = tid >> 6, lane = tid & 63;
  const int sub  = lane & 15;
  const int ggrp = blockIdx.x * 16 + wave * 4 + (lane >> 4);
  const int row  = ggrp >> 6, g = ggrp & 63;

  const float4 v = *(const float4*)(x + (size_t)row * IN_F + g * GS + sub * 4);
  float m = fmaxf(fmaxf(fabsf(v.x), fabsf(v.y)), fmaxf(fabsf(v.z), fabsf(v.w)));
  m = fmaxf(m, __shfl_xor(m, 1));
  m = fmaxf(m, __shfl_xor(m, 2));
  m = fmaxf(m, __shfl_xor(m, 4));
  m = fmaxf(m, __shfl_xor(m, 8));
  const float ascale = (m > 0.f) ? m * (1.f / 127.f) : 1.f;

  const float d0 = fminf(fmaxf(rintf(v.x / ascale), -127.f), 127.f) * ascale;
  const float d1 = fminf(fmaxf(rintf(v.y / ascale), -127.f), 127.f) * ascale;
  const float d2 = fminf(fmaxf(rintf(v.z / ascale), -127.f), 127.f) * ascale;
  const float d3 = fminf(fmaxf(rintf(v.w / ascale), -127.f), 127.f) * ascale;

  uint2 st;
  st.x = (uint)f2bf(d0) | ((uint)f2bf(d1) << 16);
  st.y = (uint)f2bf(d2) | ((uint)f2bf(d3) << 16);
  *(uint2*)(Aext + (size_t)row * KTOT + g * GS + sub * 4) = st;
}

// ---------------------------------------------------------------------------
// Kernel 2: dequant int4 weights -> B_ext[:, 0:4096] (bf16). 8 elems/thread.
// ---------------------------------------------------------------------------
__global__ __launch_bounds__(256)
void wdeq_kernel(const int* __restrict__ qw, const float* __restrict__ wsc,
                 ushort* __restrict__ Bext)
{
  const int gidx = blockIdx.x * 256 + threadIdx.x;   // over OUT_F * 512
  const int o  = gidx >> 9;
  const int i0 = (gidx & 511) << 3;
  const float sc = wsc[o * NG + (i0 >> 6)];
  const int4 qa = *(const int4*)(qw + (size_t)o * IN_F + i0);
  const int4 qb = *(const int4*)(qw + (size_t)o * IN_F + i0 + 4);
  uint4 st;
  st.x = (uint)f2bf(qa.x * sc) | ((uint)f2bf(qa.y * sc) << 16);
  st.y = (uint)f2bf(qa.z * sc) | ((uint)f2bf(qa.w * sc) << 16);
  st.z = (uint)f2bf(qb.x * sc) | ((uint)f2bf(qb.y * sc) << 16);
  st.w = (uint)f2bf(qb.z * sc) | ((uint)f2bf(qb.w * sc) << 16);
  *(uint4*)(Bext + (size_t)o * KTOT + i0) = st;
}

// ---------------------------------------------------------------------------
// Kernel 3 (aux): pu^T -> B_ext[:, 4096:4128] + zero pad; pd -> pdT (bf16).
// ---------------------------------------------------------------------------
__global__ __launch_bounds__(256)
void aux_kernel(const float* __restrict__ pd, const float* __restrict__ pu,
                ushort* __restrict__ Bext, ushort* __restrict__ pdT)
{
  const int id = blockIdx.x * 256 + threadIdx.x;   // 0..4095
  ushort* dst = Bext + (size_t)id * KTOT + IN_F;
  #pragma unroll
  for (int r = 0; r < RANK; ++r) {
    dst[r]        = f2bf(pu[(size_t)r * OUT_F + id]);
    dst[RANK + r] = 0;
  }
  #pragma unroll
  for (int r = 0; r < RANK; ++r)
    pdT[(size_t)r * IN_F + id] = f2bf(pd[(size_t)id * RANK + r]);
}

// ---------------------------------------------------------------------------
// Kernel 4: lr partials = Aq @ pdT^T via MFMA.
// Grid 256 = 64 M-tiles (64 rows) x 4 K-chunks (1024). 4 waves/block, each
// wave: 16 rows x 32 cols. Same staging swizzle as the main GEMM.
// ---------------------------------------------------------------------------
__global__ __launch_bounds__(256)
void lr_kernel(const ushort* __restrict__ A, const ushort* __restrict__ pdT,
               float* __restrict__ part)
{
  __shared__ alignas(16) ushort lA[64 * 64];   // 8 KB
  const int tid  = threadIdx.x;
  const int wave = tid >> 6, lane = tid & 63;
  const int mt = blockIdx.x >> 2;              // 0..63
  const int kc = blockIdx.x & 3;               // 0..3
  const int k0 = kc * KCH;

  const int tr  = tid >> 3;                    // 0..31
  const int scc = (tid & 7) ^ (tr & 7);
  const ushort* aSrc = A + (size_t)(mt * 64 + tr) * KTOT + k0 + scc * 8;
  char* ldsA = (char*)lA + wave * 1024;

  f32x4 acc[2];
  #pragma unroll
  for (int n = 0; n < 2; ++n) acc[n] = f32x4{0.f, 0.f, 0.f, 0.f};

  for (int kt = 0; kt < KCH / 64; ++kt) {
    const ushort* aS = aSrc + kt * 64;
    #pragma unroll
    for (int j = 0; j < 2; ++j)
      __builtin_amdgcn_global_load_lds(
          (const __attribute__((address_space(1))) void*)(aS + (size_t)j * 32 * KTOT),
          (__attribute__((address_space(3))) void*)(ldsA + j * 4096), 16, 0, 0);
    __syncthreads();
    #pragma unroll
    for (int ks = 0; ks < 2; ++ks) {
      const int kb  = (ks * 32 + (lane >> 4) * 8) * 2;
      const int row = wave * 16 + (lane & 15);
      const int addr = (row * 128 + kb) ^ ((row & 7) << 4);
      bf16x8 af = *(const bf16x8*)((const char*)lA + addr);
      #pragma unroll
      for (int n = 0; n < 2; ++n) {
        const int prow = n * 16 + (lane & 15);
        bf16x8 bf = *(const bf16x8*)(pdT + (size_t)prow * IN_F + k0 + kt * 64 + ks * 32 + (lane >> 4) * 8);
        acc[n] = __builtin_amdgcn_mfma_f32_16x16x32_bf16(af, bf, acc[n], 0, 0, 0);
      }
    }
    __syncthreads();
  }
  const int r0   = lane & 15;
  const int rowb = mt * 64 + wave * 16 + (lane >> 4) * 4;
  #pragma unroll
  for (int n = 0; n < 2; ++n)
    #pragma unroll
    for (int i = 0; i < 4; ++i)
      part[((size_t)kc * 4096 + rowb + i) * 32 + n * 16 + r0] = acc[n][i];
}

// ---------------------------------------------------------------------------
// Kernel 5: combine lr partials -> A_ext[:, 4096:4128] bf16, zero 4128:4160.
// ---------------------------------------------------------------------------
__global__ __launch_bounds__(256)
void lrcomb_kernel(const float* __restrict__ part, ushort* __restrict__ Aext)
{
  const int id  = blockIdx.x * 256 + threadIdx.x;  // 0..131071
  const int row = id >> 5, r = id & 31;
  const float s = part[(size_t)row * 32 + r]
                + part[(size_t)(4096 + row) * 32 + r]
                + part[(size_t)(8192 + row) * 32 + r]
                + part[(size_t)(12288 + row) * 32 + r];
  Aext[(size_t)row * KTOT + IN_F + r]        = f2bf(s);
  Aext[(size_t)row * KTOT + IN_F + RANK + r] = 0;
}

// ---------------------------------------------------------------------------
// Kernel 6: C = A_ext @ B_ext^T + bias.  128x128 tile, BK=64, 4 waves,
// global_load_lds(16B) staging, XOR-swizzled LDS, 16x16x32 bf16 MFMA,
// XCD-aware block swizzle (T1, 1024 % 8 == 0 -> bijective).
// ---------------------------------------------------------------------------
__global__ __launch_bounds__(256, 2)
void gemm_kernel(const ushort* __restrict__ A, const ushort* __restrict__ B,
                 const float* __restrict__ bias, float* __restrict__ C)
{
  __shared__ alignas(16) ushort lA[128 * 64];
  __shared__ alignas(16) ushort lB[128 * 64];
  const int tid  = threadIdx.x;
  const int wave = tid >> 6, lane = tid & 63;
  const int wg = (blockIdx.x & 7) * 128 + (blockIdx.x >> 3);   // XCD swizzle
  const int bm = wg >> 5, bn = wg & 31;
  const int wm = wave >> 1, wn = wave & 1;

  const int tr  = tid >> 3;
  const int scc = (tid & 7) ^ (tr & 7);
  const ushort* aSrc = A + (size_t)(bm * 128 + tr) * KTOT + scc * 8;
  const ushort* bSrc = B + (size_t)(bn * 128 + tr) * KTOT + scc * 8;
  char* ldsA = (char*)lA + wave * 1024;   // wave-uniform LDS bases
  char* ldsB = (char*)lB + wave * 1024;

  f32x4 acc[4][4];
  #pragma unroll
  for (int m = 0; m < 4; ++m)
    #pragma unroll
    for (int n = 0; n < 4; ++n)
      acc[m][n] = f32x4{0.f, 0.f, 0.f, 0.f};

  for (int kt = 0; kt < KTOT / 64; ++kt) {
    const ushort* aS = aSrc + kt * 64;
    const ushort* bS = bSrc + kt * 64;
    #pragma unroll
    for (int j = 0; j < 4; ++j)
      __builtin_amdgcn_global_load_lds(
          (const __attribute__((address_space(1))) void*)(aS + (size_t)j * 32 * KTOT),
          (__attribute__((address_space(3))) void*)(ldsA + j * 4096), 16, 0, 0);
    #pragma unroll
    for (int j = 0; j < 4; ++j)
      __builtin_amdgcn_global_load_lds(
          (const __attribute__((address_space(1))) void*)(bS + (size_t)j * 32 * KTOT),
          (__attribute__((address_space(3))) void*)(ldsB + j * 4096), 16, 0, 0);
    __syncthreads();

    #pragma unroll
    for (int ks = 0; ks < 2; ++ks) {
      const int kb = (ks * 32 + (lane >> 4) * 8) * 2;   // byte offset of k
      bf16x8 af[4], bfr[4];
      #pragma unroll
      for (int m = 0; m < 4; ++m) {
        const int row  = wm * 64 + m * 16 + (lane & 15);
        const int addr = (row * 128 + kb) ^ ((row & 7) << 4);
        af[m] = *(const bf16x8*)((const char*)lA + addr);
      }
      #pragma unroll
      for (int n = 0; n < 4; ++n) {
        const int row  = wn * 64 + n * 16 + (lane & 15);
        const int addr = (row * 128 + kb) ^ ((row & 7) << 4);
        bfr[n] = *(const bf16x8*)((const char*)lB + addr);
      }
      #pragma unroll
      for (int m = 0; m < 4; ++m)
        #pragma unroll
        for (int n = 0; n < 4; ++n)
          acc[m][n] = __builtin_amdgcn_mfma_f32_16x16x32_bf16(af[m], bfr[n], acc[m][n], 0, 0, 0);
    }
    __syncthreads();
  }

  const int col0  = bn * 128 + wn * 64 + (lane & 15);
  const int rbase = bm * 128 + wm * 64 + (lane >> 4) * 4;
  #pragma unroll
  for (int n = 0; n < 4; ++n) {
    const float bv = bias[col0 + n * 16];
    #pragma unroll
    for (int m = 0; m < 4; ++m) {
      #pragma unroll
      for (int i = 0; i < 4; ++i)
        C[(size_t)(rbase + m * 16 + i) * OUT_F + col0 + n * 16] = acc[m][n][i] + bv;
    }
  }
}

// ---------------------------------------------------------------------------
extern "C" void kernel_launch(void* const* d_in, const int* in_sizes, int n_in,
                              void* d_out, int out_size, void* d_ws, size_t ws_size,
                              hipStream_t stream) {
  const float* x    = (const float*)d_in[0];
  const int*   qw   = (const int*)d_in[1];
  const float* wsc  = (const float*)d_in[2];
  const float* bias = (const float*)d_in[3];
  const float* pd   = (const float*)d_in[4];
  const float* pu   = (const float*)d_in[5];
  float* out = (float*)d_out;

  ushort* Aext = (ushort*)d_ws;                        // [4096][4160] bf16
  ushort* Bext = Aext + (size_t)NTOK * KTOT;           // [4096][4160] bf16
  ushort* pdT  = Bext + (size_t)OUT_F * KTOT;          // [32][4096] bf16
  float*  part = (float*)(pdT + (size_t)RANK * IN_F);  // [4][4096][32] f32

  quant_kernel <<<16384, 256, 0, stream>>>(x, Aext);
  wdeq_kernel  <<< 8192, 256, 0, stream>>>(qw, wsc, Bext);
  aux_kernel   <<<   16, 256, 0, stream>>>(pd, pu, Bext, pdT);
  lr_kernel    <<<  256, 256, 0, stream>>>(Aext, pdT, part);
  lrcomb_kernel<<<  512, 256, 0, stream>>>(part, Aext);
  gemm_kernel  <<< 1024, 256, 0, stream>>>(Aext, Bext, bias, out);
}

// Round 3
// 202.225 us; speedup vs baseline: 1.1596x; 1.0045x over previous
//
#include <hip/hip_runtime.h>
#include <hip/hip_bf16.h>

#define IN_F  4096
#define OUT_F 4096
#define NTOK  4096
#define RANK  32
#define GS    64
#define NG    64
#define KTOT  4224          // 4096 + 32 (low-rank) + 96 zero pad -> 66 * 64
#define NKT   66
#define ITERS 33
#define KCH   1024

typedef __attribute__((ext_vector_type(4))) float f32x4;
typedef __attribute__((ext_vector_type(8))) short bf16x8;

__device__ __forceinline__ ushort f2bf(float f) {
  union { float f; uint u; } c; c.f = f;
  const uint u = c.u;
  return (ushort)((u + 0x7fffu + ((u >> 16) & 1u)) >> 16);  // RNE
}

// ---------------------------------------------------------------------------
// Kernel 1: per-group int8 quant + dequant of x -> A_ext[:, 0:4096] (bf16)
// ---------------------------------------------------------------------------
__global__ __launch_bounds__(256)
void quant_kernel(const float* __restrict__ x, ushort* __restrict__ Aext)
{
  const int tid  = threadIdx.x;
  const int wave = tid >> 6, lane = tid & 63;
  const int sub  = lane & 15;
  const int ggrp = blockIdx.x * 16 + wave * 4 + (lane >> 4);
  const int row  = ggrp >> 6, g = ggrp & 63;

  const float4 v = *(const float4*)(x + (size_t)row * IN_F + g * GS + sub * 4);
  float m = fmaxf(fmaxf(fabsf(v.x), fabsf(v.y)), fmaxf(fabsf(v.z), fabsf(v.w)));
  m = fmaxf(m, __shfl_xor(m, 1));
  m = fmaxf(m, __shfl_xor(m, 2));
  m = fmaxf(m, __shfl_xor(m, 4));
  m = fmaxf(m, __shfl_xor(m, 8));
  const float ascale = (m > 0.f) ? m * (1.f / 127.f) : 1.f;

  const float d0 = fminf(fmaxf(rintf(v.x / ascale), -127.f), 127.f) * ascale;
  const float d1 = fminf(fmaxf(rintf(v.y / ascale), -127.f), 127.f) * ascale;
  const float d2 = fminf(fmaxf(rintf(v.z / ascale), -127.f), 127.f) * ascale;
  const float d3 = fminf(fmaxf(rintf(v.w / ascale), -127.f), 127.f) * ascale;

  uint2 st;
  st.x = (uint)f2bf(d0) | ((uint)f2bf(d1) << 16);
  st.y = (uint)f2bf(d2) | ((uint)f2bf(d3) << 16);
  *(uint2*)(Aext + (size_t)row * KTOT + g * GS + sub * 4) = st;
}

// ---------------------------------------------------------------------------
// Kernel 2: dequant int4 weights -> B_ext[:, 0:4096] (bf16)
// ---------------------------------------------------------------------------
__global__ __launch_bounds__(256)
void wdeq_kernel(const int* __restrict__ qw, const float* __restrict__ wsc,
                 ushort* __restrict__ Bext)
{
  const int gidx = blockIdx.x * 256 + threadIdx.x;
  const int o  = gidx >> 9;
  const int i0 = (gidx & 511) << 3;
  const float sc = wsc[o * NG + (i0 >> 6)];
  const int4 qa = *(const int4*)(qw + (size_t)o * IN_F + i0);
  const int4 qb = *(const int4*)(qw + (size_t)o * IN_F + i0 + 4);
  uint4 st;
  st.x = (uint)f2bf(qa.x * sc) | ((uint)f2bf(qa.y * sc) << 16);
  st.y = (uint)f2bf(qa.z * sc) | ((uint)f2bf(qa.w * sc) << 16);
  st.z = (uint)f2bf(qb.x * sc) | ((uint)f2bf(qb.y * sc) << 16);
  st.w = (uint)f2bf(qb.z * sc) | ((uint)f2bf(qb.w * sc) << 16);
  *(uint4*)(Bext + (size_t)o * KTOT + i0) = st;
}

// ---------------------------------------------------------------------------
// Kernel 3 (aux): pu^T -> B_ext[:, 4096:4128] + zero pad 4128:4224; pd -> pdT.
// ---------------------------------------------------------------------------
__global__ __launch_bounds__(256)
void aux_kernel(const float* __restrict__ pd, const float* __restrict__ pu,
                ushort* __restrict__ Bext, ushort* __restrict__ pdT)
{
  const int id = blockIdx.x * 256 + threadIdx.x;   // 0..4095
  ushort* dst = Bext + (size_t)id * KTOT + IN_F;
  #pragma unroll
  for (int r = 0; r < RANK; ++r) {
    dst[r]            = f2bf(pu[(size_t)r * OUT_F + id]);
    dst[RANK + r]     = 0;
    dst[2 * RANK + r] = 0;
    dst[3 * RANK + r] = 0;
  }
  #pragma unroll
  for (int r = 0; r < RANK; ++r)
    pdT[(size_t)r * IN_F + id] = f2bf(pd[(size_t)id * RANK + r]);
}

// ---------------------------------------------------------------------------
// Kernel 4: lr partials = Aq @ pdT^T via MFMA (64 M-tiles x 4 K-chunks).
// ---------------------------------------------------------------------------
__global__ __launch_bounds__(256)
void lr_kernel(const ushort* __restrict__ A, const ushort* __restrict__ pdT,
               float* __restrict__ part)
{
  __shared__ alignas(16) ushort lA[64 * 64];
  const int tid  = threadIdx.x;
  const int wave = tid >> 6, lane = tid & 63;
  const int mt = blockIdx.x >> 2;
  const int kc = blockIdx.x & 3;
  const int k0 = kc * KCH;

  const int tr  = tid >> 3;
  const int scc = (tid & 7) ^ (tr & 7);
  const ushort* aSrc = A + (size_t)(mt * 64 + tr) * KTOT + k0 + scc * 8;
  char* ldsA = (char*)lA + wave * 1024;

  f32x4 acc[2];
  #pragma unroll
  for (int n = 0; n < 2; ++n) acc[n] = f32x4{0.f, 0.f, 0.f, 0.f};

  for (int kt = 0; kt < KCH / 64; ++kt) {
    const ushort* aS = aSrc + kt * 64;
    #pragma unroll
    for (int j = 0; j < 2; ++j)
      __builtin_amdgcn_global_load_lds(
          (const __attribute__((address_space(1))) void*)(aS + (size_t)j * 32 * KTOT),
          (__attribute__((address_space(3))) void*)(ldsA + j * 4096), 16, 0, 0);
    __syncthreads();
    #pragma unroll
    for (int ks = 0; ks < 2; ++ks) {
      const int kb  = (ks * 32 + (lane >> 4) * 8) * 2;
      const int row = wave * 16 + (lane & 15);
      const int addr = (row * 128 + kb) ^ ((row & 7) << 4);
      bf16x8 af = *(const bf16x8*)((const char*)lA + addr);
      #pragma unroll
      for (int n = 0; n < 2; ++n) {
        const int prow = n * 16 + (lane & 15);
        bf16x8 bf = *(const bf16x8*)(pdT + (size_t)prow * IN_F + k0 + kt * 64 + ks * 32 + (lane >> 4) * 8);
        acc[n] = __builtin_amdgcn_mfma_f32_16x16x32_bf16(af, bf, acc[n], 0, 0, 0);
      }
    }
    __syncthreads();
  }
  const int r0   = lane & 15;
  const int rowb = mt * 64 + wave * 16 + (lane >> 4) * 4;
  #pragma unroll
  for (int n = 0; n < 2; ++n)
    #pragma unroll
    for (int i = 0; i < 4; ++i)
      part[((size_t)kc * 4096 + rowb + i) * 32 + n * 16 + r0] = acc[n][i];
}

// ---------------------------------------------------------------------------
// Kernel 5: combine lr partials -> A_ext[:, 4096:4128], zero 4128:4224.
// ---------------------------------------------------------------------------
__global__ __launch_bounds__(256)
void lrcomb_kernel(const float* __restrict__ part, ushort* __restrict__ Aext)
{
  const int id  = blockIdx.x * 256 + threadIdx.x;
  const int row = id >> 5, r = id & 31;
  const float s = part[(size_t)row * 32 + r]
                + part[(size_t)(4096 + row) * 32 + r]
                + part[(size_t)(8192 + row) * 32 + r]
                + part[(size_t)(12288 + row) * 32 + r];
  ushort* dst = Aext + (size_t)row * KTOT + IN_F;
  dst[r]            = f2bf(s);
  dst[RANK + r]     = 0;
  dst[2 * RANK + r] = 0;
  dst[3 * RANK + r] = 0;
}

// ---------------------------------------------------------------------------
// Kernel 6: 256x256 8-phase GEMM (T2+T3+T4+T5). C = A_ext @ B_ext^T + bias.
// LDS: A buf b at b*32768 (quarter q of 64 rows at +q*8192),
//      B at 65536 + b*32768 (quarter = brow>>6).  XOR swizzle ((r&7)<<4).
// A-half h = quarters {h, h+2}; B-half h = within-quarter rows [h*32, h*32+32).
// ---------------------------------------------------------------------------
__device__ __forceinline__ void stageA(const ushort* __restrict__ Atile, char* lds,
                                       int b, int h, int kt, int w, int lane)
{
  #pragma unroll
  for (int l = 0; l < 2; ++l) {
    const int g = w * 2 + l;
    const int quarter = h + (g >> 3) * 2;
    const int sub = g & 7;
    const int grow = quarter * 64 + sub * 8 + (lane >> 3);
    const ushort* src = Atile + (size_t)grow * KTOT + kt * 64 + (((lane & 7) ^ (lane >> 3)) << 3);
    __builtin_amdgcn_global_load_lds(
        (const __attribute__((address_space(1))) void*)src,
        (__attribute__((address_space(3))) void*)(lds + b * 32768 + quarter * 8192 + sub * 1024),
        16, 0, 0);
  }
}

__device__ __forceinline__ void stageB(const ushort* __restrict__ Btile, char* lds,
                                       int b, int h, int kt, int w, int lane)
{
  #pragma unroll
  for (int l = 0; l < 2; ++l) {
    const int g = w * 2 + l;
    const int j = g >> 2;
    const int sub = g & 3;
    const int grow = j * 64 + h * 32 + sub * 8 + (lane >> 3);
    const ushort* src = Btile + (size_t)grow * KTOT + kt * 64 + (((lane & 7) ^ (lane >> 3)) << 3);
    __builtin_amdgcn_global_load_lds(
        (const __attribute__((address_space(1))) void*)src,
        (__attribute__((address_space(3))) void*)(lds + 65536 + b * 32768 + j * 8192 + h * 4096 + sub * 1024),
        16, 0, 0);
  }
}

// One phase: 12 ds_read_b128 + stage + barrier + 16 MFMA + [vmcnt] + barrier.
#define PHASE(B_, MQ_, NQ_, STAGE, WAIT4)                                        \
  {                                                                              \
    bf16x8 af[4][2], bfm[2][2];                                                  \
    const int aqb = (B_) * 32768 + (wm * 2 + (MQ_)) * 8192;                      \
    const int bqb = 65536 + (B_) * 32768 + wn * 8192;                            \
    _Pragma("unroll")                                                            \
    for (int mf = 0; mf < 4; ++mf) {                                             \
      const int r = mf * 16 + l15;                                               \
      _Pragma("unroll")                                                          \
      for (int ks = 0; ks < 2; ++ks)                                             \
        af[mf][ks] = *(const bf16x8*)(lds + aqb + (((r * 128) + kbyte[ks]) ^ ((r & 7) << 4))); \
    }                                                                            \
    _Pragma("unroll")                                                            \
    for (int nf = 0; nf < 2; ++nf) {                                             \
      const int r = ((NQ_) * 2 + nf) * 16 + l15;                                 \
      _Pragma("unroll")                                                          \
      for (int ks = 0; ks < 2; ++ks)                                             \
        bfm[nf][ks] = *(const bf16x8*)(lds + bqb + (((r * 128) + kbyte[ks]) ^ ((r & 7) << 4))); \
    }                                                                            \
    STAGE;                                                                       \
    __builtin_amdgcn_s_barrier();                                                \
    __builtin_amdgcn_s_setprio(1);                                               \
    _Pragma("unroll")                                                            \
    for (int mf = 0; mf < 4; ++mf)                                               \
      _Pragma("unroll")                                                          \
      for (int nf = 0; nf < 2; ++nf)                                             \
        _Pragma("unroll")                                                        \
        for (int ks = 0; ks < 2; ++ks)                                           \
          acc[(MQ_) * 4 + mf][(NQ_) * 2 + nf] =                                  \
              __builtin_amdgcn_mfma_f32_16x16x32_bf16(af[mf][ks], bfm[nf][ks],   \
                  acc[(MQ_) * 4 + mf][(NQ_) * 2 + nf], 0, 0, 0);                 \
    __builtin_amdgcn_s_setprio(0);                                               \
    if (WAIT4) asm volatile("s_waitcnt vmcnt(4)" ::: "memory");                  \
    __builtin_amdgcn_s_barrier();                                                \
  }

__global__ __launch_bounds__(512, 2)
void gemm256_kernel(const ushort* __restrict__ A, const ushort* __restrict__ B,
                    const float* __restrict__ bias, float* __restrict__ C)
{
  extern __shared__ char lds[];
  const int tid = threadIdx.x;
  const int w = tid >> 6, lane = tid & 63;
  const int l15 = lane & 15;
  const int wm = w >> 2, wn = w & 3;          // 2 x 4 waves
  int kbyte[2];
  kbyte[0] = ((lane >> 4) * 8) * 2;
  kbyte[1] = (32 + (lane >> 4) * 8) * 2;

  // 2-D XCD chunk swizzle: each XCD gets a 4x8 (bm x bn) region.
  const int xcd = blockIdx.x & 7, idx = blockIdx.x >> 3;
  const int bm = (xcd >> 1) * 4 + (idx >> 3);
  const int bn = (xcd & 1) * 8 + (idx & 7);

  const ushort* Atile = A + (size_t)bm * 256 * KTOT;
  const ushort* Btile = B + (size_t)bn * 256 * KTOT;

  f32x4 acc[8][4];
  #pragma unroll
  for (int m = 0; m < 8; ++m)
    #pragma unroll
    for (int n = 0; n < 4; ++n)
      acc[m][n] = f32x4{0.f, 0.f, 0.f, 0.f};

  // Prologue: buf0 <- tile 0 (all 4 halves), buf1 <- tile 1 (A_H0, B_H0).
  stageA(Atile, lds, 0, 0, 0, w, lane);
  stageB(Btile, lds, 0, 0, 0, w, lane);
  stageB(Btile, lds, 0, 1, 0, w, lane);
  stageA(Atile, lds, 0, 1, 0, w, lane);
  stageA(Atile, lds, 1, 0, 1, w, lane);
  stageB(Btile, lds, 1, 0, 1, w, lane);
  asm volatile("s_waitcnt vmcnt(4)" ::: "memory");
  __builtin_amdgcn_s_barrier();

  #pragma unroll 1
  for (int j = 0; j < ITERS; ++j) {
    const int t1 = 2 * j + 1, t2 = 2 * j + 2, t3 = 2 * j + 3;
    PHASE(0, 0, 0, { stageB(Btile, lds, 1, 1, t1, w, lane); }, 0)
    PHASE(0, 0, 1, { stageA(Atile, lds, 1, 1, t1, w, lane); }, 0)
    PHASE(0, 1, 0, { if (t2 < NKT) stageA(Atile, lds, 0, 0, t2, w, lane); }, 0)
    PHASE(0, 1, 1, { if (t2 < NKT) stageB(Btile, lds, 0, 0, t2, w, lane); }, 1)
    PHASE(1, 0, 0, { if (t2 < NKT) stageB(Btile, lds, 0, 1, t2, w, lane); }, 0)
    PHASE(1, 0, 1, { if (t2 < NKT) stageA(Atile, lds, 0, 1, t2, w, lane); }, 0)
    PHASE(1, 1, 0, { if (t3 < NKT) stageA(Atile, lds, 1, 0, t3, w, lane); }, 0)
    PHASE(1, 1, 1, { if (t3 < NKT) stageB(Btile, lds, 1, 0, t3, w, lane); }, 1)
  }

  // Epilogue: C = acc + bias. acc frag: col = l15, row = (lane>>4)*4 + i.
  const int csub = lane >> 4;
  #pragma unroll
  for (int nf = 0; nf < 4; ++nf) {
    const int col = bn * 256 + wn * 64 + nf * 16 + l15;
    const float bv = bias[col];
    #pragma unroll
    for (int mf = 0; mf < 8; ++mf) {
      const int row = bm * 256 + wm * 128 + mf * 16 + csub * 4;
      #pragma unroll
      for (int i = 0; i < 4; ++i)
        C[(size_t)(row + i) * OUT_F + col] = acc[mf][nf][i] + bv;
    }
  }
}

// ---------------------------------------------------------------------------
extern "C" void kernel_launch(void* const* d_in, const int* in_sizes, int n_in,
                              void* d_out, int out_size, void* d_ws, size_t ws_size,
                              hipStream_t stream) {
  const float* x    = (const float*)d_in[0];
  const int*   qw   = (const int*)d_in[1];
  const float* wsc  = (const float*)d_in[2];
  const float* bias = (const float*)d_in[3];
  const float* pd   = (const float*)d_in[4];
  const float* pu   = (const float*)d_in[5];
  float* out = (float*)d_out;

  ushort* Aext = (ushort*)d_ws;                        // [4096][4224] bf16
  ushort* Bext = Aext + (size_t)NTOK * KTOT;           // [4096][4224] bf16
  ushort* pdT  = Bext + (size_t)OUT_F * KTOT;          // [32][4096] bf16
  float*  part = (float*)(pdT + (size_t)RANK * IN_F);  // [4][4096][32] f32

  hipFuncSetAttribute(reinterpret_cast<const void*>(gemm256_kernel),
                      hipFuncAttributeMaxDynamicSharedMemorySize, 131072);

  quant_kernel <<<16384, 256, 0, stream>>>(x, Aext);
  wdeq_kernel  <<< 8192, 256, 0, stream>>>(qw, wsc, Bext);
  aux_kernel   <<<   16, 256, 0, stream>>>(pd, pu, Bext, pdT);
  lr_kernel    <<<  256, 256, 0, stream>>>(Aext, pdT, part);
  lrcomb_kernel<<<  512, 256, 0, stream>>>(part, Aext);
  gemm256_kernel<<< 256, 512, 131072, stream>>>(Aext, Bext, bias, out);
}

// Round 4
// 186.980 us; speedup vs baseline: 1.2542x; 1.0815x over previous
//
#include <hip/hip_runtime.h>
#include <hip/hip_bf16.h>

#define IN_F  4096
#define OUT_F 4096
#define NTOK  4096
#define RANK  32
#define GS    64
#define NG    64
#define KTOT  4224          // 4096 + 32 (low-rank) + 96 zero pad -> 66 * 64
#define NKT   66
#define ITERS 33
#define KCH   1024

typedef __attribute__((ext_vector_type(4))) float f32x4;
typedef __attribute__((ext_vector_type(8))) short bf16x8;

__device__ __forceinline__ ushort f2bf(float f) {
  union { float f; uint u; } c; c.f = f;
  const uint u = c.u;
  return (ushort)((u + 0x7fffu + ((u >> 16) & 1u)) >> 16);  // RNE
}

// ---------------------------------------------------------------------------
// Kernel 1: per-group int8 quant + dequant of x -> A_ext[:, 0:4096] (bf16)
// ---------------------------------------------------------------------------
__global__ __launch_bounds__(256)
void quant_kernel(const float* __restrict__ x, ushort* __restrict__ Aext)
{
  const int tid  = threadIdx.x;
  const int wave = tid >> 6, lane = tid & 63;
  const int sub  = lane & 15;
  const int ggrp = blockIdx.x * 16 + wave * 4 + (lane >> 4);
  const int row  = ggrp >> 6, g = ggrp & 63;

  const float4 v = *(const float4*)(x + (size_t)row * IN_F + g * GS + sub * 4);
  float m = fmaxf(fmaxf(fabsf(v.x), fabsf(v.y)), fmaxf(fabsf(v.z), fabsf(v.w)));
  m = fmaxf(m, __shfl_xor(m, 1));
  m = fmaxf(m, __shfl_xor(m, 2));
  m = fmaxf(m, __shfl_xor(m, 4));
  m = fmaxf(m, __shfl_xor(m, 8));
  const float ascale = (m > 0.f) ? m * (1.f / 127.f) : 1.f;

  const float d0 = fminf(fmaxf(rintf(v.x / ascale), -127.f), 127.f) * ascale;
  const float d1 = fminf(fmaxf(rintf(v.y / ascale), -127.f), 127.f) * ascale;
  const float d2 = fminf(fmaxf(rintf(v.z / ascale), -127.f), 127.f) * ascale;
  const float d3 = fminf(fmaxf(rintf(v.w / ascale), -127.f), 127.f) * ascale;

  uint2 st;
  st.x = (uint)f2bf(d0) | ((uint)f2bf(d1) << 16);
  st.y = (uint)f2bf(d2) | ((uint)f2bf(d3) << 16);
  *(uint2*)(Aext + (size_t)row * KTOT + g * GS + sub * 4) = st;
}

// ---------------------------------------------------------------------------
// Kernel 2: dequant int4 weights -> B_ext[:, 0:4096] (bf16)
// ---------------------------------------------------------------------------
__global__ __launch_bounds__(256)
void wdeq_kernel(const int* __restrict__ qw, const float* __restrict__ wsc,
                 ushort* __restrict__ Bext)
{
  const int gidx = blockIdx.x * 256 + threadIdx.x;
  const int o  = gidx >> 9;
  const int i0 = (gidx & 511) << 3;
  const float sc = wsc[o * NG + (i0 >> 6)];
  const int4 qa = *(const int4*)(qw + (size_t)o * IN_F + i0);
  const int4 qb = *(const int4*)(qw + (size_t)o * IN_F + i0 + 4);
  uint4 st;
  st.x = (uint)f2bf(qa.x * sc) | ((uint)f2bf(qa.y * sc) << 16);
  st.y = (uint)f2bf(qa.z * sc) | ((uint)f2bf(qa.w * sc) << 16);
  st.z = (uint)f2bf(qb.x * sc) | ((uint)f2bf(qb.y * sc) << 16);
  st.w = (uint)f2bf(qb.z * sc) | ((uint)f2bf(qb.w * sc) << 16);
  *(uint4*)(Bext + (size_t)o * KTOT + i0) = st;
}

// ---------------------------------------------------------------------------
// Kernel 3 (aux): pu^T -> B_ext[:, 4096:4128] + zero pad 4128:4224; pd -> pdT.
// ---------------------------------------------------------------------------
__global__ __launch_bounds__(256)
void aux_kernel(const float* __restrict__ pd, const float* __restrict__ pu,
                ushort* __restrict__ Bext, ushort* __restrict__ pdT)
{
  const int id = blockIdx.x * 256 + threadIdx.x;   // 0..4095
  ushort* dst = Bext + (size_t)id * KTOT + IN_F;
  #pragma unroll
  for (int r = 0; r < RANK; ++r) {
    dst[r]            = f2bf(pu[(size_t)r * OUT_F + id]);
    dst[RANK + r]     = 0;
    dst[2 * RANK + r] = 0;
    dst[3 * RANK + r] = 0;
  }
  #pragma unroll
  for (int r = 0; r < RANK; ++r)
    pdT[(size_t)r * IN_F + id] = f2bf(pd[(size_t)id * RANK + r]);
}

// ---------------------------------------------------------------------------
// Kernel 4: lr partials = Aq @ pdT^T via MFMA (64 M-tiles x 4 K-chunks).
// ---------------------------------------------------------------------------
__global__ __launch_bounds__(256)
void lr_kernel(const ushort* __restrict__ A, const ushort* __restrict__ pdT,
               float* __restrict__ part)
{
  __shared__ alignas(16) ushort lA[64 * 64];
  const int tid  = threadIdx.x;
  const int wave = tid >> 6, lane = tid & 63;
  const int mt = blockIdx.x >> 2;
  const int kc = blockIdx.x & 3;
  const int k0 = kc * KCH;

  const int tr  = tid >> 3;
  const int scc = (tid & 7) ^ (tr & 7);
  const ushort* aSrc = A + (size_t)(mt * 64 + tr) * KTOT + k0 + scc * 8;
  char* ldsA = (char*)lA + wave * 1024;

  f32x4 acc[2];
  #pragma unroll
  for (int n = 0; n < 2; ++n) acc[n] = f32x4{0.f, 0.f, 0.f, 0.f};

  for (int kt = 0; kt < KCH / 64; ++kt) {
    const ushort* aS = aSrc + kt * 64;
    #pragma unroll
    for (int j = 0; j < 2; ++j)
      __builtin_amdgcn_global_load_lds(
          (const __attribute__((address_space(1))) void*)(aS + (size_t)j * 32 * KTOT),
          (__attribute__((address_space(3))) void*)(ldsA + j * 4096), 16, 0, 0);
    __syncthreads();
    #pragma unroll
    for (int ks = 0; ks < 2; ++ks) {
      const int kb  = (ks * 32 + (lane >> 4) * 8) * 2;
      const int row = wave * 16 + (lane & 15);
      const int addr = (row * 128 + kb) ^ ((row & 7) << 4);
      bf16x8 af = *(const bf16x8*)((const char*)lA + addr);
      #pragma unroll
      for (int n = 0; n < 2; ++n) {
        const int prow = n * 16 + (lane & 15);
        bf16x8 bf = *(const bf16x8*)(pdT + (size_t)prow * IN_F + k0 + kt * 64 + ks * 32 + (lane >> 4) * 8);
        acc[n] = __builtin_amdgcn_mfma_f32_16x16x32_bf16(af, bf, acc[n], 0, 0, 0);
      }
    }
    __syncthreads();
  }
  const int r0   = lane & 15;
  const int rowb = mt * 64 + wave * 16 + (lane >> 4) * 4;
  #pragma unroll
  for (int n = 0; n < 2; ++n)
    #pragma unroll
    for (int i = 0; i < 4; ++i)
      part[((size_t)kc * 4096 + rowb + i) * 32 + n * 16 + r0] = acc[n][i];
}

// ---------------------------------------------------------------------------
// Kernel 5: combine lr partials -> A_ext[:, 4096:4128], zero 4128:4224.
// ---------------------------------------------------------------------------
__global__ __launch_bounds__(256)
void lrcomb_kernel(const float* __restrict__ part, ushort* __restrict__ Aext)
{
  const int id  = blockIdx.x * 256 + threadIdx.x;
  const int row = id >> 5, r = id & 31;
  const float s = part[(size_t)row * 32 + r]
                + part[(size_t)(4096 + row) * 32 + r]
                + part[(size_t)(8192 + row) * 32 + r]
                + part[(size_t)(12288 + row) * 32 + r];
  ushort* dst = Aext + (size_t)row * KTOT + IN_F;
  dst[r]            = f2bf(s);
  dst[RANK + r]     = 0;
  dst[2 * RANK + r] = 0;
  dst[3 * RANK + r] = 0;
}

// ---------------------------------------------------------------------------
// Kernel 6: 256x256 8-phase GEMM (T2+T3+T4+T5). C = A_ext @ B_ext^T + bias.
// LDS: A buf b at b*32768 (quarter q of 64 rows at +q*8192),
//      B at 65536 + b*32768 (quarter = brow>>6).  XOR swizzle ((r&7)<<4).
// A-half h = quarters {h, h+2}; B-half h = within-quarter rows [h*32, h*32+32).
// R4 change: af[4][2] loaded only in NQ==0 phases, HELD across the NQ==1
// phase (m201 read discipline: A read once per K-tile, 4-or-12 ds_reads/phase).
// ---------------------------------------------------------------------------
__device__ __forceinline__ void stageA(const ushort* __restrict__ Atile, char* lds,
                                       int b, int h, int kt, int w, int lane)
{
  #pragma unroll
  for (int l = 0; l < 2; ++l) {
    const int g = w * 2 + l;
    const int quarter = h + (g >> 3) * 2;
    const int sub = g & 7;
    const int grow = quarter * 64 + sub * 8 + (lane >> 3);
    const ushort* src = Atile + (size_t)grow * KTOT + kt * 64 + (((lane & 7) ^ (lane >> 3)) << 3);
    __builtin_amdgcn_global_load_lds(
        (const __attribute__((address_space(1))) void*)src,
        (__attribute__((address_space(3))) void*)(lds + b * 32768 + quarter * 8192 + sub * 1024),
        16, 0, 0);
  }
}

__device__ __forceinline__ void stageB(const ushort* __restrict__ Btile, char* lds,
                                       int b, int h, int kt, int w, int lane)
{
  #pragma unroll
  for (int l = 0; l < 2; ++l) {
    const int g = w * 2 + l;
    const int j = g >> 2;
    const int sub = g & 3;
    const int grow = j * 64 + h * 32 + sub * 8 + (lane >> 3);
    const ushort* src = Btile + (size_t)grow * KTOT + kt * 64 + (((lane & 7) ^ (lane >> 3)) << 3);
    __builtin_amdgcn_global_load_lds(
        (const __attribute__((address_space(1))) void*)src,
        (__attribute__((address_space(3))) void*)(lds + 65536 + b * 32768 + j * 8192 + h * 4096 + sub * 1024),
        16, 0, 0);
  }
}

// One phase: [8 af ds_reads if READA] + 4 bfm ds_reads + stage + barrier +
// 16 MFMA (setprio-wrapped) + [vmcnt(4)] + barrier.
#define PHASE(B_, MQ_, NQ_, READA, STAGE, WAIT4)                                 \
  {                                                                              \
    bf16x8 bfm[2][2];                                                            \
    if (READA) {                                                                 \
      const int aqb = (B_) * 32768 + (wm * 2 + (MQ_)) * 8192;                    \
      _Pragma("unroll")                                                          \
      for (int mf = 0; mf < 4; ++mf) {                                           \
        const int r = mf * 16 + l15;                                             \
        _Pragma("unroll")                                                        \
        for (int ks = 0; ks < 2; ++ks)                                           \
          af[mf][ks] = *(const bf16x8*)(lds + aqb + (((r * 128) + kbyte[ks]) ^ ((r & 7) << 4))); \
      }                                                                          \
    }                                                                            \
    {                                                                            \
      const int bqb = 65536 + (B_) * 32768 + wn * 8192;                          \
      _Pragma("unroll")                                                          \
      for (int nf = 0; nf < 2; ++nf) {                                           \
        const int r = ((NQ_) * 2 + nf) * 16 + l15;                               \
        _Pragma("unroll")                                                        \
        for (int ks = 0; ks < 2; ++ks)                                           \
          bfm[nf][ks] = *(const bf16x8*)(lds + bqb + (((r * 128) + kbyte[ks]) ^ ((r & 7) << 4))); \
      }                                                                          \
    }                                                                            \
    STAGE;                                                                       \
    __builtin_amdgcn_s_barrier();                                                \
    __builtin_amdgcn_s_setprio(1);                                               \
    _Pragma("unroll")                                                            \
    for (int mf = 0; mf < 4; ++mf)                                               \
      _Pragma("unroll")                                                          \
      for (int nf = 0; nf < 2; ++nf)                                             \
        _Pragma("unroll")                                                        \
        for (int ks = 0; ks < 2; ++ks)                                           \
          acc[(MQ_) * 4 + mf][(NQ_) * 2 + nf] =                                  \
              __builtin_amdgcn_mfma_f32_16x16x32_bf16(af[mf][ks], bfm[nf][ks],   \
                  acc[(MQ_) * 4 + mf][(NQ_) * 2 + nf], 0, 0, 0);                 \
    __builtin_amdgcn_s_setprio(0);                                               \
    if (WAIT4) asm volatile("s_waitcnt vmcnt(4)" ::: "memory");                  \
    __builtin_amdgcn_s_barrier();                                                \
  }

__global__ __launch_bounds__(512, 2)
void gemm256_kernel(const ushort* __restrict__ A, const ushort* __restrict__ B,
                    const float* __restrict__ bias, float* __restrict__ C)
{
  extern __shared__ char lds[];
  const int tid = threadIdx.x;
  const int w = tid >> 6, lane = tid & 63;
  const int l15 = lane & 15;
  const int wm = w >> 2, wn = w & 3;          // 2 x 4 waves
  int kbyte[2];
  kbyte[0] = ((lane >> 4) * 8) * 2;
  kbyte[1] = (32 + (lane >> 4) * 8) * 2;

  // 2-D XCD chunk swizzle: each XCD gets a 4x8 (bm x bn) region.
  const int xcd = blockIdx.x & 7, idx = blockIdx.x >> 3;
  const int bm = (xcd >> 1) * 4 + (idx >> 3);
  const int bn = (xcd & 1) * 8 + (idx & 7);

  const ushort* Atile = A + (size_t)bm * 256 * KTOT;
  const ushort* Btile = B + (size_t)bn * 256 * KTOT;

  f32x4 acc[8][4];
  #pragma unroll
  for (int m = 0; m < 8; ++m)
    #pragma unroll
    for (int n = 0; n < 4; ++n)
      acc[m][n] = f32x4{0.f, 0.f, 0.f, 0.f};

  // Prologue: buf0 <- tile 0 (all 4 halves), buf1 <- tile 1 (A_H0, B_H0).
  stageA(Atile, lds, 0, 0, 0, w, lane);
  stageB(Btile, lds, 0, 0, 0, w, lane);
  stageB(Btile, lds, 0, 1, 0, w, lane);
  stageA(Atile, lds, 0, 1, 0, w, lane);
  stageA(Atile, lds, 1, 0, 1, w, lane);
  stageB(Btile, lds, 1, 0, 1, w, lane);
  asm volatile("s_waitcnt vmcnt(4)" ::: "memory");
  __builtin_amdgcn_s_barrier();

  #pragma unroll 1
  for (int j = 0; j < ITERS; ++j) {
    const int t1 = 2 * j + 1, t2 = 2 * j + 2, t3 = 2 * j + 3;
    bf16x8 af[4][2];   // held across the NQ==1 phase of each quadrant pair
    PHASE(0, 0, 0, 1, { stageB(Btile, lds, 1, 1, t1, w, lane); }, 0)
    PHASE(0, 0, 1, 0, { stageA(Atile, lds, 1, 1, t1, w, lane); }, 0)
    PHASE(0, 1, 0, 1, { if (t2 < NKT) stageA(Atile, lds, 0, 0, t2, w, lane); }, 0)
    PHASE(0, 1, 1, 0, { if (t2 < NKT) stageB(Btile, lds, 0, 0, t2, w, lane); }, 1)
    PHASE(1, 0, 0, 1, { if (t2 < NKT) stageB(Btile, lds, 0, 1, t2, w, lane); }, 0)
    PHASE(1, 0, 1, 0, { if (t2 < NKT) stageA(Atile, lds, 0, 1, t2, w, lane); }, 0)
    PHASE(1, 1, 0, 1, { if (t3 < NKT) stageA(Atile, lds, 1, 0, t3, w, lane); }, 0)
    PHASE(1, 1, 1, 0, { if (t3 < NKT) stageB(Btile, lds, 1, 0, t3, w, lane); }, 1)
  }

  // Epilogue: C = acc + bias. acc frag: col = l15, row = (lane>>4)*4 + i.
  const int csub = lane >> 4;
  #pragma unroll
  for (int nf = 0; nf < 4; ++nf) {
    const int col = bn * 256 + wn * 64 + nf * 16 + l15;
    const float bv = bias[col];
    #pragma unroll
    for (int mf = 0; mf < 8; ++mf) {
      const int row = bm * 256 + wm * 128 + mf * 16 + csub * 4;
      #pragma unroll
      for (int i = 0; i < 4; ++i)
        C[(size_t)(row + i) * OUT_F + col] = acc[mf][nf][i] + bv;
    }
  }
}

// ---------------------------------------------------------------------------
extern "C" void kernel_launch(void* const* d_in, const int* in_sizes, int n_in,
                              void* d_out, int out_size, void* d_ws, size_t ws_size,
                              hipStream_t stream) {
  const float* x    = (const float*)d_in[0];
  const int*   qw   = (const int*)d_in[1];
  const float* wsc  = (const float*)d_in[2];
  const float* bias = (const float*)d_in[3];
  const float* pd   = (const float*)d_in[4];
  const float* pu   = (const float*)d_in[5];
  float* out = (float*)d_out;

  ushort* Aext = (ushort*)d_ws;                        // [4096][4224] bf16
  ushort* Bext = Aext + (size_t)NTOK * KTOT;           // [4096][4224] bf16
  ushort* pdT  = Bext + (size_t)OUT_F * KTOT;          // [32][4096] bf16
  float*  part = (float*)(pdT + (size_t)RANK * IN_F);  // [4][4096][32] f32

  hipFuncSetAttribute(reinterpret_cast<const void*>(gemm256_kernel),
                      hipFuncAttributeMaxDynamicSharedMemorySize, 131072);

  quant_kernel <<<16384, 256, 0, stream>>>(x, Aext);
  wdeq_kernel  <<< 8192, 256, 0, stream>>>(qw, wsc, Bext);
  aux_kernel   <<<   16, 256, 0, stream>>>(pd, pu, Bext, pdT);
  lr_kernel    <<<  256, 256, 0, stream>>>(Aext, pdT, part);
  lrcomb_kernel<<<  512, 256, 0, stream>>>(part, Aext);
  gemm256_kernel<<< 256, 512, 131072, stream>>>(Aext, Bext, bias, out);
}